// Round 1
// baseline (553.038 us; speedup 1.0000x reference)
//
#include <hip/hip_runtime.h>
#include <hip/hip_bf16.h>

// CycleFC: out[b,o,h,w] = bias[o] + sum_c weight[o,c] * x[b,c,h,w+s[c]]
//   s[c] = ((c+3) % 7) - 3, zero pad when w+s[c] outside [0,56)
// GEMM view: M=C_out=256, K=C_in=256, N=B*H*W=200704 (bf16 MFMA, fp32 acc)

#define CIN  256
#define HW   3136     // 56*56
#define WID  56
#define NT   49       // pixel tiles per batch (3136 / 64)

typedef __attribute__((ext_vector_type(8))) short short8;
using f32x4 = __attribute__((ext_vector_type(4))) float;

__device__ inline unsigned short f2bf(float f) {
    union { float f; unsigned u; } v; v.f = f;
    unsigned r = v.u + 0x7fffu + ((v.u >> 16) & 1u);   // RNE
    return (unsigned short)(r >> 16);
}

__global__ __launch_bounds__(256, 4)
void cyclefc_kernel(const float* __restrict__ x,
                    const float* __restrict__ weight,
                    const float* __restrict__ bias,
                    float* __restrict__ out) {
    // LDS tiles, both [row][k] bf16 with XOR swizzle (byte ^= (row&7)<<4)
    __shared__ __align__(16) unsigned short lA[256 * 64];  // weight tile, 32 KB
    __shared__ __align__(16) unsigned short lB[64 * 64];   // shifted-x tile, 8 KB

    const int t   = threadIdx.x;
    const int l   = t & 63;
    const int wid = t >> 6;
    const int bx  = blockIdx.x;
    const int b   = bx / NT;
    const int tile = bx - b * NT;
    const int n0  = tile * 64;

    const int wm = wid >> 1;      // wave row (0..1) -> 128 M each
    const int wn = wid & 1;       // wave col (0..1) -> 32 N each
    const int mbase = wm * 128;
    const int nbase = wn * 32;

    const int l15 = l & 15;
    const int lg  = l >> 4;

    // accumulators initialized with bias (bias[o] broadcast over pixels)
    f32x4 acc[8][2];
    #pragma unroll
    for (int mf = 0; mf < 8; ++mf) {
        int o4 = mbase + mf * 16 + lg * 4;
        float4 bv = *reinterpret_cast<const float4*>(bias + o4);
        f32x4 a; a[0] = bv.x; a[1] = bv.y; a[2] = bv.z; a[3] = bv.w;
        acc[mf][0] = a; acc[mf][1] = a;
    }

    const int pix = n0 + l;             // this lane's pixel within batch b
    const int w   = pix % WID;          // position within the 56-wide row
    const size_t xbase = (size_t)b * CIN * HW + (size_t)pix;

    char* lAc = (char*)lA;
    char* lBc = (char*)lB;

    for (int k0 = 0; k0 < CIN; k0 += 64) {
        if (k0) __syncthreads();

        // ---- stage A: weight[m][k0..k0+64) -> lA, fp32->bf16, swizzled ----
        {
            const int q = t & 7;                       // 16B chunk within 128B row
            #pragma unroll
            for (int i = 0; i < 8; ++i) {
                int m = (t + 256 * i) >> 3;            // 0..255
                const float4* wp = reinterpret_cast<const float4*>(weight + m * 256 + k0 + q * 8);
                float4 f0 = wp[0];
                float4 f1 = wp[1];
                uint4 pk;
                pk.x = f2bf(f0.x) | ((unsigned)f2bf(f0.y) << 16);
                pk.y = f2bf(f0.z) | ((unsigned)f2bf(f0.w) << 16);
                pk.z = f2bf(f1.x) | ((unsigned)f2bf(f1.y) << 16);
                pk.w = f2bf(f1.z) | ((unsigned)f2bf(f1.w) << 16);
                *(uint4*)(lAc + m * 128 + ((q * 16) ^ ((m & 7) << 4))) = pk;
            }
        }

        // ---- stage B: shifted x -> lB[n][k], fp32->bf16, swizzled ----
        // wave `wid` stages channels c in [k0+16*wid, k0+16*wid+16), lane = pixel
        {
            unsigned short vb[16];
            #pragma unroll
            for (int ci = 0; ci < 16; ++ci) {
                int c  = k0 + wid * 16 + ci;
                int sc = ((c + 3) % 7) - 3;            // wave-uniform
                int wv = w + sc;
                float xv = 0.0f;
                if ((unsigned)wv < (unsigned)WID)
                    xv = x[xbase + (size_t)c * HW + sc];
                vb[ci] = f2bf(xv);
            }
            uint4 p0, p1;
            p0.x = vb[0]  | ((unsigned)vb[1]  << 16);
            p0.y = vb[2]  | ((unsigned)vb[3]  << 16);
            p0.z = vb[4]  | ((unsigned)vb[5]  << 16);
            p0.w = vb[6]  | ((unsigned)vb[7]  << 16);
            p1.x = vb[8]  | ((unsigned)vb[9]  << 16);
            p1.y = vb[10] | ((unsigned)vb[11] << 16);
            p1.z = vb[12] | ((unsigned)vb[13] << 16);
            p1.w = vb[14] | ((unsigned)vb[15] << 16);
            const int kb  = wid * 32;                  // byte offset of this wave's 16 channels
            const int swz = (l & 7) << 4;
            *(uint4*)(lBc + l * 128 + ( kb        ^ swz)) = p0;
            *(uint4*)(lBc + l * 128 + ((kb + 16)  ^ swz)) = p1;
        }

        __syncthreads();

        // ---- compute: 2 k-chunks of 32, 8 M-frags x 2 N-frags ----
        #pragma unroll
        for (int kc = 0; kc < 2; ++kc) {
            const int kbb = kc * 64 + lg * 16;         // byte offset of this lane's 8 bf16
            short8 bfrag[2];
            #pragma unroll
            for (int nf = 0; nf < 2; ++nf) {
                int r = nbase + nf * 16 + l15;
                bfrag[nf] = *reinterpret_cast<const short8*>(lBc + r * 128 + (kbb ^ ((r & 7) << 4)));
            }
            #pragma unroll
            for (int mf = 0; mf < 8; ++mf) {
                int r = mbase + mf * 16 + l15;
                short8 afrag = *reinterpret_cast<const short8*>(lAc + r * 128 + (kbb ^ ((r & 7) << 4)));
                acc[mf][0] = __builtin_amdgcn_mfma_f32_16x16x32_bf16(afrag, bfrag[0], acc[mf][0], 0, 0, 0);
                acc[mf][1] = __builtin_amdgcn_mfma_f32_16x16x32_bf16(afrag, bfrag[1], acc[mf][1], 0, 0, 0);
            }
        }
    }

    // ---- epilogue: C layout col=lane&15 (pixel), row=(lane>>4)*4+j (out ch) ----
    #pragma unroll
    for (int mf = 0; mf < 8; ++mf) {
        #pragma unroll
        for (int nf = 0; nf < 2; ++nf) {
            int col = n0 + nbase + nf * 16 + l15;
            #pragma unroll
            for (int j = 0; j < 4; ++j) {
                int o = mbase + mf * 16 + lg * 4 + j;
                out[((size_t)b * CIN + o) * HW + col] = acc[mf][nf][j];
            }
        }
    }
}

extern "C" void kernel_launch(void* const* d_in, const int* in_sizes, int n_in,
                              void* d_out, int out_size, void* d_ws, size_t ws_size,
                              hipStream_t stream) {
    const float* x    = (const float*)d_in[0];
    const float* wgt  = (const float*)d_in[1];
    const float* bias = (const float*)d_in[2];
    float* out        = (float*)d_out;

    dim3 grid(64 * NT);   // 3136 blocks: batch-major, 49 pixel tiles each
    dim3 block(256);
    cyclefc_kernel<<<grid, block, 0, stream>>>(x, wgt, bias, out);
}

// Round 2
// 362.076 us; speedup vs baseline: 1.5274x; 1.5274x over previous
//
#include <hip/hip_runtime.h>
#include <hip/hip_bf16.h>

// CycleFC: out[b,o,h,w] = bias[o] + sum_c weight[o,c] * x[b,c,h,w+s[c]]
//   s[c] = ((c+3) % 7) - 3, zero pad when w+s[c] outside [0,56)
// GEMM view: M=C_out=256, K=C_in=256, N=B*H*W=200704 (bf16 MFMA, fp32 acc)
//
// R2: weight prepacked to bf16 frag-ready layout in d_ws (A read straight
// from L2, no A LDS tile); x double-buffered in LDS with early-issue loads;
// 512-thread blocks; XCD-aware block swizzle.

#define CIN  256
#define HW   3136     // 56*56
#define WID  56
#define NT   49       // 64-pixel tiles per batch plane (3136 / 64)

typedef __attribute__((ext_vector_type(8))) short short8;
using f32x4 = __attribute__((ext_vector_type(4))) float;

__device__ inline unsigned short f2bf(float f) {
    union { float f; unsigned u; } v; v.f = f;
    unsigned r = v.u + 0x7fffu + ((v.u >> 16) & 1u);   // RNE
    return (unsigned short)(r >> 16);
}

// ---- prepack: weight fp32 [256][256] -> bf16 MFMA-frag layout in ws ----
// frag index: ((kt*2 + kc)*16 + g)*64 + l   (16 B per lane)
// lane l of frag (kt,kc,g) holds weight[g*16 + (l&15)][kt*64 + kc*32 + (l>>4)*8 + j], j=0..7
__global__ void prepack_kernel(const float* __restrict__ w,
                               unsigned short* __restrict__ ws) {
    int t   = blockIdx.x * 512 + threadIdx.x;   // 8192 threads total
    int l   = t & 63;
    int g   = (t >> 6) & 15;
    int kc  = (t >> 10) & 1;
    int kt  = t >> 11;
    int row = g * 16 + (l & 15);
    int kb  = kt * 64 + kc * 32 + (l >> 4) * 8;
    const float* src = w + row * 256 + kb;
    float4 f0 = *reinterpret_cast<const float4*>(src);
    float4 f1 = *reinterpret_cast<const float4*>(src + 4);
    uint4 pk;
    pk.x = f2bf(f0.x) | ((unsigned)f2bf(f0.y) << 16);
    pk.y = f2bf(f0.z) | ((unsigned)f2bf(f0.w) << 16);
    pk.z = f2bf(f1.x) | ((unsigned)f2bf(f1.y) << 16);
    pk.w = f2bf(f1.z) | ((unsigned)f2bf(f1.w) << 16);
    reinterpret_cast<uint4*>(ws)[t] = pk;
}

__global__ __launch_bounds__(512, 4)
void cyclefc_kernel(const float* __restrict__ x,
                    const unsigned short* __restrict__ wpk,
                    const float* __restrict__ bias,
                    float* __restrict__ out) {
    // B tile only: [64 pixels][64 k] bf16, XOR-swizzled, double-buffered (2x8KB)
    __shared__ __align__(16) unsigned short lB[2][64 * 64];

    const int t   = threadIdx.x;
    const int l   = t & 63;
    const int wid = t >> 6;

    // bijective XCD swizzle: 3136 blocks, 3136/8 = 392 per XCD (contiguous tiles)
    const int bx  = blockIdx.x;
    const int sbx = (bx & 7) * 392 + (bx >> 3);
    const int b    = sbx / NT;
    const int tile = sbx - b * NT;
    const int n0   = tile * 64;

    const int wm = wid >> 1;          // 0..3 -> 64 M rows each
    const int wn = wid & 1;           // 0..1 -> 32 pixels each
    const int mbase = wm * 64;
    const int nbase = wn * 32;
    const int l15 = l & 15;
    const int lg  = l >> 4;

    // accumulators seeded with bias
    f32x4 acc[4][2];
    #pragma unroll
    for (int mf = 0; mf < 4; ++mf) {
        float4 bv = *reinterpret_cast<const float4*>(bias + mbase + mf * 16 + lg * 4);
        f32x4 a; a[0] = bv.x; a[1] = bv.y; a[2] = bv.z; a[3] = bv.w;
        acc[mf][0] = a; acc[mf][1] = a;
    }

    // ---- B staging mapping: thread = (pixel p = l, channel-octet q = wid) ----
    const int p = l;
    const int q = wid;
    const int pix = n0 + p;
    const int w   = pix % WID;
    const float* xb = x + (size_t)b * CIN * HW + (size_t)pix;
    char* lB0 = (char*)lB[0];
    char* lB1 = (char*)lB[1];

    float xr[8];
    auto loadx = [&](int kt) {
        #pragma unroll
        for (int j = 0; j < 8; ++j) {
            int c  = kt * 64 + q * 8 + j;
            int sc = ((c + 3) % 7) - 3;          // wave-uniform per j
            const float* px = xb + (size_t)c * HW;
            xr[j] = ((unsigned)(w + sc) < (unsigned)WID) ? px[sc] : 0.0f;
        }
    };
    auto writeB = [&](char* base) {
        uint4 pk;
        pk.x = f2bf(xr[0]) | ((unsigned)f2bf(xr[1]) << 16);
        pk.y = f2bf(xr[2]) | ((unsigned)f2bf(xr[3]) << 16);
        pk.z = f2bf(xr[4]) | ((unsigned)f2bf(xr[5]) << 16);
        pk.w = f2bf(xr[6]) | ((unsigned)f2bf(xr[7]) << 16);
        *reinterpret_cast<uint4*>(base + p * 128 + ((q * 16) ^ ((p & 7) << 4))) = pk;
    };

    // prologue: stage k-step 0
    loadx(0);
    writeB(lB0);
    int cur = 0;

    #pragma unroll
    for (int kt = 0; kt < 4; ++kt) {
        if (kt < 3) loadx(kt + 1);               // issue next x loads early
        __syncthreads();                          // B[cur] visible

        const char* bb = cur ? lB1 : lB0;
        #pragma unroll
        for (int kc = 0; kc < 2; ++kc) {
            short8 bf[2];
            #pragma unroll
            for (int nf = 0; nf < 2; ++nf) {
                int r = nbase + nf * 16 + l15;
                bf[nf] = *reinterpret_cast<const short8*>(
                    bb + r * 128 + ((kc * 64 + lg * 16) ^ ((r & 7) << 4)));
            }
            #pragma unroll
            for (int mf = 0; mf < 4; ++mf) {
                int g = wm * 4 + mf;
                short8 af = *reinterpret_cast<const short8*>(
                    wpk + ((((kt * 2 + kc) * 16 + g) * 64 + l) << 3));
                acc[mf][0] = __builtin_amdgcn_mfma_f32_16x16x32_bf16(af, bf[0], acc[mf][0], 0, 0, 0);
                acc[mf][1] = __builtin_amdgcn_mfma_f32_16x16x32_bf16(af, bf[1], acc[mf][1], 0, 0, 0);
            }
        }
        if (kt < 3) writeB(cur ? lB0 : lB1);     // fill other buffer
        cur ^= 1;
    }

    // ---- epilogue: C layout col=l15 (pixel), row=lg*4+j (out ch); nf innermost
    //      so both 64B halves of each 128B line are adjacent stores ----
    #pragma unroll
    for (int mf = 0; mf < 4; ++mf) {
        #pragma unroll
        for (int j = 0; j < 4; ++j) {
            int o = mbase + mf * 16 + lg * 4 + j;
            float* orow = out + ((size_t)b * CIN + o) * HW + n0 + nbase;
            orow[l15]      = acc[mf][0][j];
            orow[16 + l15] = acc[mf][1][j];
        }
    }
}

extern "C" void kernel_launch(void* const* d_in, const int* in_sizes, int n_in,
                              void* d_out, int out_size, void* d_ws, size_t ws_size,
                              hipStream_t stream) {
    const float* x    = (const float*)d_in[0];
    const float* wgt  = (const float*)d_in[1];
    const float* bias = (const float*)d_in[2];
    float* out        = (float*)d_out;
    unsigned short* wpk = (unsigned short*)d_ws;   // 128 KB frag-packed weight

    prepack_kernel<<<16, 512, 0, stream>>>(wgt, wpk);
    cyclefc_kernel<<<64 * NT, 512, 0, stream>>>(x, wpk, bias, out);
}